// Round 5
// baseline (22.888 us; speedup 1.0000x reference)
//
#include <hip/hip_runtime.h>

// Shapes: proposals (16, 32768, 4) f32, gt_boxes (16, 64, 5) f32
//      -> out (16, 32768, 5) f32.
#define BATCH 16
#define NPROP 32768
#define NGT   64
#define BLOCK 256
#define P     2                      // proposals per thread (adjacent pair)

__global__ __launch_bounds__(BLOCK) void match_kernel(
    const float* __restrict__ props,   // (B, N, 4)
    const float* __restrict__ gt,      // (B, M, 5)
    float* __restrict__ out)           // (B, N, 5)
{
    // Cleaned boxes: coords as float4 (ds_read_b128); a2 packed 4-per-float4
    // so the loop reads ONE b128 per 4 boxes; cls only read in the epilogue.
    __shared__ float4 sbox[NGT];
    __shared__ float4 sa2q[NGT / 4];
    __shared__ float  scls[NGT];

    const int blocksPerBatch = NPROP / (BLOCK * P);        // 64
    const int b    = blockIdx.x / blocksPerBatch;
    const int base = (blockIdx.x % blocksPerBatch) * (BLOCK * P);

    // Stage + clean GT boxes once per block. Invalid (cls == -1) becomes a
    // far-away zero-intersection box with area2 = 1 -> iou = 0; index
    // differences vs the reference's -1 encoding only occur when the final
    // output is -1 anyway (all-invalid => q = 0 <= 0.5 => -1 fill).
    if (threadIdx.x < NGT) {
        const float* g = gt + ((size_t)b * NGT + threadIdx.x) * 5;
        float x1 = g[0], y1 = g[1], x2 = g[2], y2 = g[3], c = g[4];
        float a2 = (x2 - x1) * (y2 - y1);
        if (c == -1.0f) { x1 = y1 = x2 = y2 = -1.0e4f; a2 = 1.0f; }
        sbox[threadIdx.x] = make_float4(x1, y1, x2, y2);
        reinterpret_cast<float*>(sa2q)[threadIdx.x] = a2;
        scls[threadIdx.x] = c;
    }
    __syncthreads();

    // Two ADJACENT proposals per thread: rows 2t, 2t+1 -> 40 contiguous
    // output bytes per thread (coalesced float2 stores).
    const int n0 = base + 2 * (int)threadIdx.x;
    const float4* pv = reinterpret_cast<const float4*>(props)
                     + (size_t)b * NPROP + n0;
    float4 p[P];
    float  a1[P];
    #pragma unroll
    for (int k = 0; k < P; ++k) {
        p[k]  = pv[k];
        a1[k] = (p[k].z - p[k].x) * (p[k].w - p[k].y);
    }

    // Argmax over inter/S (monotone-equivalent to IoU = inter/(S - inter)):
    // inter_a * S_b > inter_b * S_a, dens > 0. Strict '>' keeps jnp.argmax
    // first-occurrence semantics.
    float bn[P], bs[P];
    int   bi[P];
    #pragma unroll
    for (int k = 0; k < P; ++k) { bn[k] = -1.0f; bs[k] = 1.0f; bi[k] = 0; }

    #pragma unroll 4
    for (int mq = 0; mq < NGT / 4; ++mq) {
        const float4 a2q = sa2q[mq];
        const float a2s[4] = { a2q.x, a2q.y, a2q.z, a2q.w };
        #pragma unroll
        for (int j = 0; j < 4; ++j) {
            const int m = mq * 4 + j;
            const float4 g  = sbox[m];
            const float  a2 = a2s[j];
            #pragma unroll
            for (int k = 0; k < P; ++k) {
                const float ix1 = fmaxf(p[k].x, g.x);
                const float iy1 = fmaxf(p[k].y, g.y);
                const float ix2 = fminf(p[k].z, g.z);
                const float iy2 = fminf(p[k].w, g.w);
                const float inter = fmaxf(ix2 - ix1, 0.0f) * fmaxf(iy2 - iy1, 0.0f);
                const float S     = a1[k] + a2;          // numpy's fl(a1+a2)

                const bool better = inter * bs[k] > bn[k] * S;
                bn[k] = better ? inter : bn[k];
                bs[k] = better ? S     : bs[k];
                bi[k] = better ? m     : bi[k];
            }
        }
    }

    // Epilogue: q = bn / (bs - bn) reproduces numpy's exact rounding order
    // (den = fl(fl(a1+a2) - inter), then divide). Branch-free selects.
    float o[P * 5];
    #pragma unroll
    for (int k = 0; k < P; ++k) {
        const float den = bs[k] - bn[k];
        const float q   = bn[k] / den;
        const float4 g  = sbox[bi[k]];
        const float  gc = scls[bi[k]];

        const bool bg      = (q <= 0.5f);
        const bool neutral = (q > 0.5f) & (q < 0.6f);
        const float fill   = neutral ? -1.0e8f : -1.0f;
        const bool keep    = !(bg | neutral);

        o[k * 5 + 0] = keep ? g.x : fill;
        o[k * 5 + 1] = keep ? g.y : fill;
        o[k * 5 + 2] = keep ? g.z : fill;
        o[k * 5 + 3] = keep ? g.w : fill;
        o[k * 5 + 4] = keep ? gc  : fill;
    }

    // 40 contiguous, 8-aligned bytes -> five float2 stores.
    float2* op2 = reinterpret_cast<float2*>(out + ((size_t)b * NPROP + n0) * 5);
    #pragma unroll
    for (int j = 0; j < 5; ++j)
        op2[j] = make_float2(o[2 * j], o[2 * j + 1]);
}

extern "C" void kernel_launch(void* const* d_in, const int* in_sizes, int n_in,
                              void* d_out, int out_size, void* d_ws, size_t ws_size,
                              hipStream_t stream) {
    const float* props = (const float*)d_in[0];
    const float* gt    = (const float*)d_in[1];
    float* out = (float*)d_out;

    const int grid = BATCH * (NPROP / (BLOCK * P));   // 1024 blocks
    match_kernel<<<grid, BLOCK, 0, stream>>>(props, gt, out);
}

// Round 6
// 22.163 us; speedup vs baseline: 1.0327x; 1.0327x over previous
//
#include <hip/hip_runtime.h>

// Shapes: proposals (16, 32768, 4) f32, gt_boxes (16, 64, 5) f32
//      -> out (16, 32768, 5) f32.
#define BATCH 16
#define NPROP 32768
#define NGT   64
#define BLOCK 256

// P = 1 proposal/thread -> 2048 blocks -> 8 waves/SIMD (full occupancy).
// Box reads are wave-uniform LDS broadcasts (ds_read_b128), ~80 ds-instr per
// wave, fully hidden under the ~17.6k VALU cycles/SIMD. This is the
// maximum-TLP variant to discriminate kernel-time vs fixed-overhead.
__global__ __launch_bounds__(BLOCK) void match_kernel(
    const float* __restrict__ props,   // (B, N, 4)
    const float* __restrict__ gt,      // (B, M, 5)
    float* __restrict__ out)           // (B, N, 5)
{
    // Cleaned boxes: coords as float4 (ds_read_b128); a2 packed 4-per-float4;
    // cls touched only in the epilogue.
    __shared__ float4 sbox[NGT];
    __shared__ float4 sa2q[NGT / 4];
    __shared__ float  scls[NGT];

    const int blocksPerBatch = NPROP / BLOCK;              // 128
    const int b = blockIdx.x / blocksPerBatch;
    const int n = (blockIdx.x % blocksPerBatch) * BLOCK + threadIdx.x;

    // Stage + clean GT boxes once per block. Invalid (cls == -1) becomes a
    // far-away zero-intersection box with area2 = 1 -> iou = 0; index
    // differences vs the reference's -1 encoding only occur when the final
    // output is -1 anyway (all-invalid => q = 0 <= 0.5 => -1 fill).
    if (threadIdx.x < NGT) {
        const float* g = gt + ((size_t)b * NGT + threadIdx.x) * 5;
        float x1 = g[0], y1 = g[1], x2 = g[2], y2 = g[3], c = g[4];
        float a2 = (x2 - x1) * (y2 - y1);
        if (c == -1.0f) { x1 = y1 = x2 = y2 = -1.0e4f; a2 = 1.0f; }
        sbox[threadIdx.x] = make_float4(x1, y1, x2, y2);
        reinterpret_cast<float*>(sa2q)[threadIdx.x] = a2;
        scls[threadIdx.x] = c;
    }
    __syncthreads();

    const float4 p = reinterpret_cast<const float4*>(props)[(size_t)b * NPROP + n];
    const float a1 = (p.z - p.x) * (p.w - p.y);

    // Argmax over inter/S (monotone-equivalent to IoU = inter/(S - inter)):
    // inter_a * S_b > inter_b * S_a, all S > 0. Strict '>' keeps jnp.argmax
    // first-occurrence semantics. Iteration m = 0 is peeled (no compare).
    float bn, bs;
    int   bi = 0;
    {
        const float4 g = sbox[0];
        const float ix1 = fmaxf(p.x, g.x);
        const float iy1 = fmaxf(p.y, g.y);
        const float ix2 = fminf(p.z, g.z);
        const float iy2 = fminf(p.w, g.w);
        bn = fmaxf(ix2 - ix1, 0.0f) * fmaxf(iy2 - iy1, 0.0f);
        bs = a1 + reinterpret_cast<const float*>(sa2q)[0];
    }

    #pragma unroll 4
    for (int mq = 0; mq < NGT / 4; ++mq) {
        const float4 a2q = sa2q[mq];
        const float a2s[4] = { a2q.x, a2q.y, a2q.z, a2q.w };
        #pragma unroll
        for (int j = 0; j < 4; ++j) {
            const int m = mq * 4 + j;
            if (m == 0) continue;                      // peeled above
            const float4 g = sbox[m];
            const float ix1 = fmaxf(p.x, g.x);
            const float iy1 = fmaxf(p.y, g.y);
            const float ix2 = fminf(p.z, g.z);
            const float iy2 = fminf(p.w, g.w);
            const float inter = fmaxf(ix2 - ix1, 0.0f) * fmaxf(iy2 - iy1, 0.0f);
            const float S     = a1 + a2s[j];           // numpy's fl(a1+a2)

            const bool better = inter * bs > bn * S;
            bn = better ? inter : bn;
            bs = better ? S     : bs;
            bi = better ? m     : bi;
        }
    }

    // q = bn / (bs - bn) reproduces numpy's exact rounding order
    // (den = fl(fl(a1+a2) - inter), then divide). Branch-free selects.
    const float den = bs - bn;
    const float q   = bn / den;
    const float4 g  = sbox[bi];
    const float  gc = scls[bi];

    const bool neutral = (q > 0.5f) & (q < 0.6f);
    const float fill   = neutral ? -1.0e8f : -1.0f;
    const bool keep    = (q >= 0.6f);

    float* op = out + ((size_t)b * NPROP + n) * 5;
    op[0] = keep ? g.x : fill;
    op[1] = keep ? g.y : fill;
    op[2] = keep ? g.z : fill;
    op[3] = keep ? g.w : fill;
    op[4] = keep ? gc  : fill;
}

extern "C" void kernel_launch(void* const* d_in, const int* in_sizes, int n_in,
                              void* d_out, int out_size, void* d_ws, size_t ws_size,
                              hipStream_t stream) {
    const float* props = (const float*)d_in[0];
    const float* gt    = (const float*)d_in[1];
    float* out = (float*)d_out;

    const int grid = BATCH * (NPROP / BLOCK);   // 2048 blocks
    match_kernel<<<grid, BLOCK, 0, stream>>>(props, gt, out);
}